// Round 11
// baseline (318.426 us; speedup 1.0000x reference)
//
#include <hip/hip_runtime.h>
#include <stdint.h>

#define ED   768
#define NH   12
#define HD   64
#define SEQ  4096
#define BSZ  2
#define BHT  (BSZ*NH)          // 24
#define MTOT (BSZ*SEQ)         // 8192

typedef short bf16x8  __attribute__((ext_vector_type(8)));   // 8 bf16 (4 VGPRs)
typedef float f32x4   __attribute__((ext_vector_type(4)));
typedef float f32x16  __attribute__((ext_vector_type(16)));
typedef unsigned int u32x4 __attribute__((ext_vector_type(4)));

#define LOG2E 1.44269504088896340736f
#define C2    (0.125f * LOG2E)   // folded into Q at projection time

// fp32 -> bf16 round-to-nearest-even
__device__ __forceinline__ unsigned short f2bf(float f) {
    union { float f; uint32_t u; } v; v.f = f;
    uint32_t u = v.u;
    u += 0x7fffu + ((u >> 16) & 1u);
    return (unsigned short)(u >> 16);
}

// pack two f32 -> one u32 holding 2 bf16 (lo = first arg)
__device__ __forceinline__ uint32_t cvtpk(float lo, float hi) {
    uint32_t r;
    asm("v_cvt_pk_bf16_f32 %0, %1, %2" : "=v"(r) : "v"(lo), "v"(hi));
    return r;
}

// async global->LDS, 16B/lane; lds dst = wave-uniform base, lands at base+lane*16
__device__ __forceinline__ void cp16(const unsigned short* g, unsigned short* l) {
    __builtin_amdgcn_global_load_lds(
        (const __attribute__((address_space(1))) unsigned int*)(const void*)g,
        (__attribute__((address_space(3))) unsigned int*)(void*)l,
        16, 0, 0);
}
// XOR-swizzle: LDS 16B-chunk slot c of row r holds global chunk c^(r&7).
// Staging: lane fetches global chunk (lane&7)^(lrow&7); reads use chunk^(row&7).

// ---------------------------------------------------------------------------
// Kernel 0: one-time fp32->bf16 convert. H,Wq|Wk|Wv -> d_out scratch (dead
// until out_gemm writes); Wo -> WoB in d_ws.
// ---------------------------------------------------------------------------
#define H_CHUNKS  (MTOT * ED / 4)            // 1572864 float4s
#define W_CHUNKS  (ED * ED / 4)              // 147456 per weight
#define CVT_TOTAL (H_CHUNKS + 4 * W_CHUNKS)  // 2162688 = 8448 * 256

__global__ __launch_bounds__(256) void convert_bf16(
    const float* __restrict__ H,  const float* __restrict__ Wq,
    const float* __restrict__ Wk, const float* __restrict__ Wv,
    const float* __restrict__ Wo, unsigned short* __restrict__ dst,
    unsigned short* __restrict__ WoB) {
    int i4 = blockIdx.x * 256 + threadIdx.x;
    float4 v;
    ushort4* optr;
    if (i4 < H_CHUNKS) { v = ((const float4*)H)[i4]; optr = (ushort4*)dst + i4; }
    else {
        int j = i4 - H_CHUNKS;
        if (j < 3 * W_CHUNKS) {
            if (j < W_CHUNKS)          v = ((const float4*)Wq)[j];
            else if (j < 2 * W_CHUNKS) v = ((const float4*)Wk)[j - W_CHUNKS];
            else                       v = ((const float4*)Wv)[j - 2 * W_CHUNKS];
            optr = (ushort4*)dst + i4;
        } else {
            v = ((const float4*)Wo)[j - 3 * W_CHUNKS];
            optr = (ushort4*)WoB + (j - 3 * W_CHUNKS);
        }
    }
    ushort4 o;
    o.x = f2bf(v.x); o.y = f2bf(v.y); o.z = f2bf(v.z); o.w = f2bf(v.w);
    *optr = o;
}

// ---------------------------------------------------------------------------
// Kernel 1: QKV projection, 128x128 tile, BK=64, global_load_lds + XOR swizzle.
// Q written pre-scaled by C2.  Q,K -> [b][h][s][d];  V -> [b][h][d][s].
// ---------------------------------------------------------------------------
__global__ __launch_bounds__(256) void qkv_gemm(
    const unsigned short* __restrict__ Hb,   // [8192][768] bf16
    const unsigned short* __restrict__ Wb,   // [2304][768] bf16 (Wq|Wk|Wv)
    unsigned short* __restrict__ qkv) {
    __shared__ __align__(16) unsigned short Ah[128 * 64];
    __shared__ __align__(16) unsigned short Bh[128 * 64];
    const int t = threadIdx.x, w = t >> 6, lane = t & 63;
    const int quad = lane >> 4, r16 = lane & 15;
    const int wm = w >> 1, wn = w & 1;
    const int m0 = blockIdx.y * 128, n0g = blockIdx.x * 128;
    const int wsel = n0g / ED, n0 = n0g % ED;
    const int lrow = lane >> 3;
    const int lchs = ((lane & 7) ^ (lrow & 7)) * 8;   // swizzled source chunk

    f32x4 acc[4][4] = {};
    for (int kt = 0; kt < ED / 64; ++kt) {
        const int k0 = kt * 64;
#pragma unroll
        for (int i = 0; i < 4; ++i) {
            int row = i * 32 + w * 8;
            cp16(&Hb[(size_t)(m0 + row + lrow) * ED + k0 + lchs], &Ah[row * 64]);
            cp16(&Wb[(size_t)(n0g + row + lrow) * ED + k0 + lchs], &Bh[row * 64]);
        }
        __syncthreads();
#pragma unroll
        for (int kk = 0; kk < 2; ++kk) {
            bf16x8 aF[4], bF[4];
#pragma unroll
            for (int mi = 0; mi < 4; ++mi) {
                int R = wm * 64 + mi * 16 + r16;
                aF[mi] = *(const bf16x8*)&Ah[R * 64 + (((kk * 4 + quad) ^ (r16 & 7)) * 8)];
            }
#pragma unroll
            for (int ni = 0; ni < 4; ++ni) {
                int R = wn * 64 + ni * 16 + r16;
                bF[ni] = *(const bf16x8*)&Bh[R * 64 + (((kk * 4 + quad) ^ (r16 & 7)) * 8)];
            }
            if (wsel == 2) {   // V: compute C^T so V^T stores stay coalesced
#pragma unroll
                for (int mi = 0; mi < 4; ++mi)
#pragma unroll
                    for (int ni = 0; ni < 4; ++ni)
                        acc[mi][ni] = __builtin_amdgcn_mfma_f32_16x16x32_bf16(
                            bF[ni], aF[mi], acc[mi][ni], 0, 0, 0);
            } else {
#pragma unroll
                for (int mi = 0; mi < 4; ++mi)
#pragma unroll
                    for (int ni = 0; ni < 4; ++ni)
                        acc[mi][ni] = __builtin_amdgcn_mfma_f32_16x16x32_bf16(
                            aF[mi], bF[ni], acc[mi][ni], 0, 0, 0);
            }
        }
        __syncthreads();
    }
    const size_t WSZ = (size_t)BHT * SEQ * HD;
    if (wsel == 2) {
#pragma unroll
        for (int mi = 0; mi < 4; ++mi)
#pragma unroll
            for (int ni = 0; ni < 4; ++ni)
#pragma unroll
                for (int r = 0; r < 4; ++r) {
                    int m  = m0 + wm * 64 + mi * 16 + r16;
                    int nn = n0 + wn * 64 + ni * 16 + quad * 4 + r;
                    int b = m >> 12, s = m & 4095;
                    int hh = nn >> 6, dd = nn & 63;
                    qkv[2 * WSZ + (((size_t)b * NH + hh) * HD + dd) * SEQ + s] =
                        f2bf(acc[mi][ni][r]);
                }
    } else {
        const float sc = (wsel == 0) ? C2 : 1.0f;
#pragma unroll
        for (int mi = 0; mi < 4; ++mi)
#pragma unroll
            for (int ni = 0; ni < 4; ++ni)
#pragma unroll
                for (int r = 0; r < 4; ++r) {
                    int m = m0 + wm * 64 + mi * 16 + quad * 4 + r;
                    int b = m >> 12, s = m & 4095;
                    int nn = n0 + wn * 64 + ni * 16 + r16;
                    int hh = nn >> 6, dd = nn & 63;
                    size_t off = (((size_t)b * NH + hh) * SEQ + s) * HD + dd;
                    qkv[(size_t)wsel * WSZ + off] = f2bf(acc[mi][ni][r] * sc);
                }
    }
}

// ---------------------------------------------------------------------------
// Kernel 2: flash attention, 32x32x16 MFMA, fixed-max softmax, Q pre-scaled.
// Round-9 theory, third submission (r9/r10 both died at container
// acquisition — no timing data, kernel never staged).
// QK ONE TILE AHEAD. r8's staging/rotation/barrier skeleton kept byte-
// identical (3-slot K, 2-slot V, mask-from-global, 40KB LDS, verified);
// only WHICH tile's QK runs between the barriers changes:
//   iter t: issue mask(t+2), cp16 K(t+2),V(t+1); vmcnt(6)+barrier
//           [drains mask(t+1), K(t+1), V(t) — all issued a full tile ago];
//           ONE MFMA region: QK(t+1) from kNxt  +  PV(t) from vCur & pF(t)
//           (18 independent MFMAs back-to-back — exp2/pack no longer
//            serializes between them);
//           exp2/pack(t+1) -> pF(t+1) overlaps PV completion; barrier.
// Slot lifetimes audited: K(t) slot dead one full iter before kFar reuse;
// V WAR covered by bottom barrier exactly as r8. Peeled: prologue QK(0);
// t=62 (vmcnt(2), no K/mask issue); final PV(63) behind vmcnt(0)+barrier.
// Spill tripwire: WRITE_SIZE ~12.3MB, VGPR <= 168.
// ---------------------------------------------------------------------------
#define QK_MFMA(KOFF, M0, M1) do {                                             \
    bf16x8 am0 = {}, am1 = {};                                                 \
    if (hi == 0) { am0[0] = (short)f2bf(LOG2E * (M0));                         \
                   am1[0] = (short)f2bf(LOG2E * (M1)); }                       \
    sA0 = __builtin_amdgcn_mfma_f32_32x32x16_bf16(am0, bOnes, Z, 0, 0, 0);     \
    sA1 = __builtin_amdgcn_mfma_f32_32x32x16_bf16(am1, bOnes, Z, 0, 0, 0);     \
_Pragma("unroll")                                                              \
    for (int kc = 0; kc < 4; ++kc) {                                           \
        bf16x8 kF = *(const bf16x8*)                                           \
            &Ksm[(KOFF) + n31 * 64 + (((2 * kc + hi) ^ sw) * 8)];              \
        sA0 = __builtin_amdgcn_mfma_f32_32x32x16_bf16(kF, qF[kc], sA0, 0, 0, 0); \
    }                                                                          \
_Pragma("unroll")                                                              \
    for (int kc = 0; kc < 4; ++kc) {                                           \
        bf16x8 kF = *(const bf16x8*)                                           \
            &Ksm[(KOFF) + (32 + n31) * 64 + (((2 * kc + hi) ^ sw) * 8)];       \
        sA1 = __builtin_amdgcn_mfma_f32_32x32x16_bf16(kF, qF[kc], sA1, 0, 0, 0); \
    }                                                                          \
} while (0)

#define PV_MFMA(VOFF, PF) do {                                                 \
_Pragma("unroll")                                                              \
    for (int kc = 0; kc < 4; ++kc) {                                           \
_Pragma("unroll")                                                              \
        for (int dt = 0; dt < 2; ++dt) {                                       \
            bf16x8 vF = *(const bf16x8*)                                       \
                &Vtsm[(VOFF) + (dt * 32 + n31) * 64 + (((2 * kc + hi) ^ sw) * 8)]; \
            oAcc[dt] = __builtin_amdgcn_mfma_f32_32x32x16_bf16(                \
                vF, PF[kc], oAcc[dt], 0, 0, 0);                                \
        }                                                                      \
    }                                                                          \
} while (0)

#define SM_PACK(PF_OUT) do {                                                   \
_Pragma("unroll")                                                              \
    for (int st = 0; st < 2; ++st) {                                           \
        float p_[16];                                                          \
        const f32x16& sA = st ? sA1 : sA0;                                     \
_Pragma("unroll")                                                              \
        for (int r = 0; r < 16; ++r) p_[r] = __builtin_amdgcn_exp2f(sA[r]);    \
        l_i += (((p_[0] + p_[1]) + (p_[2] + p_[3])) +                          \
                ((p_[4] + p_[5]) + (p_[6] + p_[7]))) +                         \
               (((p_[8] + p_[9]) + (p_[10] + p_[11])) +                        \
                ((p_[12] + p_[13]) + (p_[14] + p_[15])));                      \
        uint32_t pw[8];                                                        \
_Pragma("unroll")                                                              \
        for (int i = 0; i < 8; ++i)                                            \
            pw[i] = cvtpk(p_[2 * i], p_[2 * i + 1]);                           \
_Pragma("unroll")                                                              \
        for (int hf = 0; hf < 2; ++hf) {                                       \
            auto r02 = __builtin_amdgcn_permlane32_swap(                       \
                pw[hf * 4 + 0], pw[hf * 4 + 2], false, false);                 \
            auto r13 = __builtin_amdgcn_permlane32_swap(                       \
                pw[hf * 4 + 1], pw[hf * 4 + 3], false, false);                 \
            union { u32x4 u; bf16x8 h; } f_;                                   \
            f_.u[0] = r02[0]; f_.u[1] = r13[0]; f_.u[2] = r02[1]; f_.u[3] = r13[1]; \
            PF_OUT[st * 2 + hf] = f_.h;                                        \
        }                                                                      \
    }                                                                          \
} while (0)

__global__ __launch_bounds__(256) void flash_attn(
    const unsigned short* __restrict__ qkv, const float* __restrict__ mask,
    unsigned short* __restrict__ ctx) {
    __shared__ __align__(16) unsigned short Ksm[3 * 4096];   // 3-slot [key][dim], swizzled, 24KB
    __shared__ __align__(16) unsigned short Vtsm[2 * 4096];  // 2-slot [dim][key], swizzled, 16KB
    const int t  = threadIdx.x;
    const int bh = blockIdx.y;
    const int b  = bh / NH;
    const int h  = bh % NH;
    const int qbase = blockIdx.x * 128;
    const size_t WSZ = (size_t)BHT * SEQ * HD;
    const unsigned short* Qp = qkv + (size_t)bh * SEQ * HD;
    const unsigned short* Kp = Qp + WSZ;
    const unsigned short* Vt = qkv + 2 * WSZ + (size_t)bh * HD * SEQ;
    const int w = t >> 6, lane = t & 63, n31 = lane & 31, hi = lane >> 5;
    const int lrow = lane >> 3;
    const int lchs = ((lane & 7) ^ (lrow & 7)) * 8;

    bf16x8 qF[4];
    {
        int qrow = qbase + w * 32 + n31;
#pragma unroll
        for (int kc = 0; kc < 4; ++kc)
            qF[kc] = *(const bf16x8*)&Qp[(size_t)qrow * HD + kc * 16 + hi * 8];
    }
    bf16x8 bOnes = {};
    if (hi == 0) bOnes[0] = (short)0x3F80;   // 1.0 at k==0
    const f32x16 Z = {};

    const float* mrow = mask + (size_t)b * SEQ;
    const int row0 = w * 16, row1 = w * 16 + 8;   // this wave's staging rows

    // prologue: K(0)->slot0, K(1)->slot1, V(0)->vslot0; masks 0 and 1; drain
    cp16(&Kp[(size_t)(row0 + lrow) * HD + lchs],      &Ksm[row0 * 64]);
    cp16(&Kp[(size_t)(row1 + lrow) * HD + lchs],      &Ksm[row1 * 64]);
    cp16(&Kp[(size_t)(64 + row0 + lrow) * HD + lchs], &Ksm[4096 + row0 * 64]);
    cp16(&Kp[(size_t)(64 + row1 + lrow) * HD + lchs], &Ksm[4096 + row1 * 64]);
    cp16(&Vt[(size_t)(row0 + lrow) * SEQ + lchs],     &Vtsm[row0 * 64]);
    cp16(&Vt[(size_t)(row1 + lrow) * SEQ + lchs],     &Vtsm[row1 * 64]);
    float m00 = mrow[n31],      m01 = mrow[32 + n31];   // mask(0)
    float mA0 = mrow[64 + n31], mA1 = mrow[96 + n31];   // mask(1)
    __syncthreads();

    f32x16 oAcc[2] = {};
    float l_i = 0.0f;
    const int sw = n31 & 7;                  // row-swizzle for frag reads
    int kCur = 0, kNxt = 4096, kFar = 8192;  // rotating K slots (ushort offsets)
    int vCur = 0;                            // V slot (0 / 4096)

    // peeled QK(0) -> pFA (K(0) in slot0, drained above)
    bf16x8 pFA[4];
    {
        f32x16 sA0, sA1;
        QK_MFMA(0, m00, m01);
        SM_PACK(pFA);
    }

    for (int kt = 0; kt < 62; ++kt) {
        // issue (6 VMEM ops/iter): mask(t+2) regs + K(t+2) + V(t+1)
        float mN0 = mrow[(kt + 2) * 64 + n31];
        float mN1 = mrow[(kt + 2) * 64 + 32 + n31];
        cp16(&Kp[(size_t)((kt + 2) * 64 + row0 + lrow) * HD + lchs], &Ksm[kFar + row0 * 64]);
        cp16(&Kp[(size_t)((kt + 2) * 64 + row1 + lrow) * HD + lchs], &Ksm[kFar + row1 * 64]);
        cp16(&Vt[(size_t)(row0 + lrow) * SEQ + (kt + 1) * 64 + lchs], &Vtsm[(vCur ^ 4096) + row0 * 64]);
        cp16(&Vt[(size_t)(row1 + lrow) * SEQ + (kt + 1) * 64 + lchs], &Vtsm[(vCur ^ 4096) + row1 * 64]);

        // drains mask(t+1), K(t+1), V(t); leaves this iter's 6 in flight
        asm volatile("s_waitcnt vmcnt(6)\n\ts_barrier" ::: "memory");

        // merged MFMA region: QK(t+1) + PV(t) — 18 independent MFMAs
        f32x16 sA0, sA1;
        __builtin_amdgcn_s_setprio(1);
        QK_MFMA(kNxt, mA0, mA1);
        PV_MFMA(vCur, pFA);
        __builtin_amdgcn_s_setprio(0);

        // exp2/pack(t+1) overlaps PV completion
        bf16x8 pFB[4];
        SM_PACK(pFB);

        asm volatile("s_barrier" ::: "memory");   // WAR for slot reuse

        int tmp = kCur; kCur = kNxt; kNxt = kFar; kFar = tmp;
        vCur ^= 4096;
        mA0 = mN0; mA1 = mN1;
        pFA[0] = pFB[0]; pFA[1] = pFB[1]; pFA[2] = pFB[2]; pFA[3] = pFB[3];
    }
    // kt = 62: no K/mask issue; stage V(63); QK(63) + PV(62)
    {
        cp16(&Vt[(size_t)(row0 + lrow) * SEQ + 63 * 64 + lchs], &Vtsm[(vCur ^ 4096) + row0 * 64]);
        cp16(&Vt[(size_t)(row1 + lrow) * SEQ + 63 * 64 + lchs], &Vtsm[(vCur ^ 4096) + row1 * 64]);
        asm volatile("s_waitcnt vmcnt(2)\n\ts_barrier" ::: "memory");  // drains iter-61's 6
        f32x16 sA0, sA1;
        __builtin_amdgcn_s_setprio(1);
        QK_MFMA(kNxt, mA0, mA1);        // QK(63)
        PV_MFMA(vCur, pFA);             // PV(62)
        __builtin_amdgcn_s_setprio(0);
        bf16x8 pFB[4];
        SM_PACK(pFB);
        // V(63) must be landed in all waves' rows before PV(63)
        asm volatile("s_waitcnt vmcnt(0)\n\ts_barrier" ::: "memory");
        PV_MFMA(vCur ^ 4096, pFB);      // PV(63)
    }

    l_i += __shfl_xor(l_i, 32);
    float inv = 1.0f / l_i;
    int s = qbase + w * 32 + n31;
    unsigned short* obase = &ctx[((size_t)b * SEQ + s) * ED + h * HD];
#pragma unroll
    for (int dt = 0; dt < 2; ++dt)
#pragma unroll
        for (int g = 0; g < 4; ++g) {
            ushort4 o;
            o.x = f2bf(oAcc[dt][4 * g + 0] * inv);
            o.y = f2bf(oAcc[dt][4 * g + 1] * inv);
            o.z = f2bf(oAcc[dt][4 * g + 2] * inv);
            o.w = f2bf(oAcc[dt][4 * g + 3] * inv);
            *(ushort4*)&obase[dt * 32 + hi * 4 + 8 * g] = o;
        }
}

// ---------------------------------------------------------------------------
// Kernel 3: output projection, 128x128 tile m97-style.
// out[m][n] = sum_k ctx[m][k]*Wo[n][k] + bo[n], fp32 output.
// ---------------------------------------------------------------------------
__global__ __launch_bounds__(256) void out_gemm(
    const unsigned short* __restrict__ Ab,   // ctx bf16 [8192][768]
    const unsigned short* __restrict__ Wob,  // [768][768] bf16
    const float* __restrict__ bo, float* __restrict__ out) {
    __shared__ __align__(16) unsigned short Ah[128 * 64];
    __shared__ __align__(16) unsigned short Bh[128 * 64];
    const int t = threadIdx.x, w = t >> 6, lane = t & 63;
    const int quad = lane >> 4, r16 = lane & 15;
    const int wm = w >> 1, wn = w & 1;
    const int m0 = blockIdx.y * 128, n0 = blockIdx.x * 128;
    const int lrow = lane >> 3;
    const int lchs = ((lane & 7) ^ (lrow & 7)) * 8;

    f32x4 acc[4][4] = {};
    for (int kt = 0; kt < ED / 64; ++kt) {
        const int k0 = kt * 64;
#pragma unroll
        for (int i = 0; i < 4; ++i) {
            int row = i * 32 + w * 8;
            cp16(&Ab[(size_t)(m0 + row + lrow) * ED + k0 + lchs], &Ah[row * 64]);
            cp16(&Wob[(size_t)(n0 + row + lrow) * ED + k0 + lchs], &Bh[row * 64]);
        }
        __syncthreads();
#pragma unroll
        for (int kk = 0; kk < 2; ++kk) {
            bf16x8 aF[4], bF[4];
#pragma unroll
            for (int mi = 0; mi < 4; ++mi) {
                int R = wm * 64 + mi * 16 + r16;
                aF[mi] = *(const bf16x8*)&Ah[R * 64 + (((kk * 4 + quad) ^ (r16 & 7)) * 8)];
            }
#pragma unroll
            for (int ni = 0; ni < 4; ++ni) {
                int R = wn * 64 + ni * 16 + r16;
                bF[ni] = *(const bf16x8*)&Bh[R * 64 + (((kk * 4 + quad) ^ (r16 & 7)) * 8)];
            }
#pragma unroll
            for (int mi = 0; mi < 4; ++mi)
#pragma unroll
                for (int ni = 0; ni < 4; ++ni)
                    acc[mi][ni] = __builtin_amdgcn_mfma_f32_16x16x32_bf16(
                        aF[mi], bF[ni], acc[mi][ni], 0, 0, 0);
        }
        __syncthreads();
    }
    float bov[4];
#pragma unroll
    for (int ni = 0; ni < 4; ++ni) bov[ni] = bo[n0 + wn * 64 + ni * 16 + r16];
#pragma unroll
    for (int mi = 0; mi < 4; ++mi)
#pragma unroll
        for (int ni = 0; ni < 4; ++ni)
#pragma unroll
            for (int r = 0; r < 4; ++r) {
                int m = m0 + wm * 64 + mi * 16 + quad * 4 + r;
                int n = n0 + wn * 64 + ni * 16 + r16;
                out[(size_t)m * ED + n] = acc[mi][ni][r] + bov[ni];
            }
}

// ---------------------------------------------------------------------------
extern "C" void kernel_launch(void* const* d_in, const int* in_sizes, int n_in,
                              void* d_out, int out_size, void* d_ws, size_t ws_size,
                              hipStream_t stream) {
    const float* H    = (const float*)d_in[0];
    const float* mask = (const float*)d_in[1];
    const float* Wq   = (const float*)d_in[2];
    const float* Wk   = (const float*)d_in[3];
    const float* Wv   = (const float*)d_in[4];
    const float* Wo   = (const float*)d_in[5];
    const float* bo   = (const float*)d_in[6];
    unsigned short* ws = (unsigned short*)d_ws;
    const size_t WSZ = (size_t)BHT * SEQ * HD;
    unsigned short* qkv = ws;                           // 3*WSZ bf16
    unsigned short* ctx = ws + 3 * WSZ;                 // [8192][768] bf16
    unsigned short* WoB = ctx + (size_t)MTOT * ED;      // [768][768] bf16
    float* out = (float*)d_out;
    // d_out doubles as scratch for bf16 H and Wqkv until out_gemm overwrites it
    unsigned short* Hb = (unsigned short*)d_out;        // 6291456 elems
    unsigned short* Wb = Hb + (size_t)MTOT * ED;        // 1769472 elems

    convert_bf16<<<CVT_TOTAL / 256, 256, 0, stream>>>(H, Wq, Wk, Wv, Wo, Hb, WoB);
    qkv_gemm<<<dim3(3 * ED / 128, MTOT / 128), 256, 0, stream>>>(Hb, Wb, qkv);
    flash_attn<<<dim3(SEQ / 128, BHT), 256, 0, stream>>>(qkv, mask, ctx);
    out_gemm<<<dim3(ED / 128, MTOT / 128), 256, 0, stream>>>(ctx, WoB, bo, out);
}

// Round 12
// 288.357 us; speedup vs baseline: 1.1043x; 1.1043x over previous
//
#include <hip/hip_runtime.h>
#include <stdint.h>

#define ED   768
#define NH   12
#define HD   64
#define SEQ  4096
#define BSZ  2
#define BHT  (BSZ*NH)          // 24
#define MTOT (BSZ*SEQ)         // 8192

typedef short bf16x8  __attribute__((ext_vector_type(8)));   // 8 bf16 (4 VGPRs)
typedef float f32x4   __attribute__((ext_vector_type(4)));
typedef float f32x16  __attribute__((ext_vector_type(16)));
typedef unsigned int u32x4 __attribute__((ext_vector_type(4)));

#define LOG2E 1.44269504088896340736f
#define C2    (0.125f * LOG2E)   // folded into Q at projection time

// fp32 -> bf16 round-to-nearest-even
__device__ __forceinline__ unsigned short f2bf(float f) {
    union { float f; uint32_t u; } v; v.f = f;
    uint32_t u = v.u;
    u += 0x7fffu + ((u >> 16) & 1u);
    return (unsigned short)(u >> 16);
}

// pack two f32 -> one u32 holding 2 bf16 (lo = first arg)
__device__ __forceinline__ uint32_t cvtpk(float lo, float hi) {
    uint32_t r;
    asm("v_cvt_pk_bf16_f32 %0, %1, %2" : "=v"(r) : "v"(lo), "v"(hi));
    return r;
}

// async global->LDS, 16B/lane; lds dst = wave-uniform base, lands at base+lane*16
__device__ __forceinline__ void cp16(const unsigned short* g, unsigned short* l) {
    __builtin_amdgcn_global_load_lds(
        (const __attribute__((address_space(1))) unsigned int*)(const void*)g,
        (__attribute__((address_space(3))) unsigned int*)(void*)l,
        16, 0, 0);
}
// XOR-swizzle: LDS 16B-chunk slot c of row r holds global chunk c^(r&7).
// Staging: lane fetches global chunk (lane&7)^(lrow&7); reads use chunk^(row&7).

// ---------------------------------------------------------------------------
// Kernel 0: one-time fp32->bf16 convert. H,Wq|Wk|Wv -> d_out scratch (dead
// until out_gemm writes); Wo -> WoB in d_ws.
// ---------------------------------------------------------------------------
#define H_CHUNKS  (MTOT * ED / 4)            // 1572864 float4s
#define W_CHUNKS  (ED * ED / 4)              // 147456 per weight
#define CVT_TOTAL (H_CHUNKS + 4 * W_CHUNKS)  // 2162688 = 8448 * 256

__global__ __launch_bounds__(256) void convert_bf16(
    const float* __restrict__ H,  const float* __restrict__ Wq,
    const float* __restrict__ Wk, const float* __restrict__ Wv,
    const float* __restrict__ Wo, unsigned short* __restrict__ dst,
    unsigned short* __restrict__ WoB) {
    int i4 = blockIdx.x * 256 + threadIdx.x;
    float4 v;
    ushort4* optr;
    if (i4 < H_CHUNKS) { v = ((const float4*)H)[i4]; optr = (ushort4*)dst + i4; }
    else {
        int j = i4 - H_CHUNKS;
        if (j < 3 * W_CHUNKS) {
            if (j < W_CHUNKS)          v = ((const float4*)Wq)[j];
            else if (j < 2 * W_CHUNKS) v = ((const float4*)Wk)[j - W_CHUNKS];
            else                       v = ((const float4*)Wv)[j - 2 * W_CHUNKS];
            optr = (ushort4*)dst + i4;
        } else {
            v = ((const float4*)Wo)[j - 3 * W_CHUNKS];
            optr = (ushort4*)WoB + (j - 3 * W_CHUNKS);
        }
    }
    ushort4 o;
    o.x = f2bf(v.x); o.y = f2bf(v.y); o.z = f2bf(v.z); o.w = f2bf(v.w);
    *optr = o;
}

// ---------------------------------------------------------------------------
// Kernel 1: QKV projection, 128x128 tile, BK=64, global_load_lds + XOR swizzle.
// Round-12: + bijective XCD swizzle (T1). Grid 18x64 = 1152 blocks, 1152%8==0:
// swz = (lin&7)*144 + (lin>>3) gives each XCD 144 contiguous tiles = 8 full
// M-rows of 18 N-tiles -> A panels XCD-local instead of replicated in all 8
// L2s (default round-robin re-fetches each A panel ~8x).
// Q written pre-scaled by C2.  Q,K -> [b][h][s][d];  V -> [b][h][d][s].
// ---------------------------------------------------------------------------
__global__ __launch_bounds__(256) void qkv_gemm(
    const unsigned short* __restrict__ Hb,   // [8192][768] bf16
    const unsigned short* __restrict__ Wb,   // [2304][768] bf16 (Wq|Wk|Wv)
    unsigned short* __restrict__ qkv) {
    __shared__ __align__(16) unsigned short Ah[128 * 64];
    __shared__ __align__(16) unsigned short Bh[128 * 64];
    const int t = threadIdx.x, w = t >> 6, lane = t & 63;
    const int quad = lane >> 4, r16 = lane & 15;
    const int wm = w >> 1, wn = w & 1;
    // XCD-aware bijective remap (nwg=1152, nwg%8==0)
    const int lin = blockIdx.y * 18 + blockIdx.x;
    const int swz = (lin & 7) * 144 + (lin >> 3);
    const int bx = swz % 18, by = swz / 18;
    const int m0 = by * 128, n0g = bx * 128;
    const int wsel = n0g / ED, n0 = n0g % ED;
    const int lrow = lane >> 3;
    const int lchs = ((lane & 7) ^ (lrow & 7)) * 8;   // swizzled source chunk

    f32x4 acc[4][4] = {};
    for (int kt = 0; kt < ED / 64; ++kt) {
        const int k0 = kt * 64;
#pragma unroll
        for (int i = 0; i < 4; ++i) {
            int row = i * 32 + w * 8;
            cp16(&Hb[(size_t)(m0 + row + lrow) * ED + k0 + lchs], &Ah[row * 64]);
            cp16(&Wb[(size_t)(n0g + row + lrow) * ED + k0 + lchs], &Bh[row * 64]);
        }
        __syncthreads();
#pragma unroll
        for (int kk = 0; kk < 2; ++kk) {
            bf16x8 aF[4], bF[4];
#pragma unroll
            for (int mi = 0; mi < 4; ++mi) {
                int R = wm * 64 + mi * 16 + r16;
                aF[mi] = *(const bf16x8*)&Ah[R * 64 + (((kk * 4 + quad) ^ (r16 & 7)) * 8)];
            }
#pragma unroll
            for (int ni = 0; ni < 4; ++ni) {
                int R = wn * 64 + ni * 16 + r16;
                bF[ni] = *(const bf16x8*)&Bh[R * 64 + (((kk * 4 + quad) ^ (r16 & 7)) * 8)];
            }
            if (wsel == 2) {   // V: compute C^T so V^T stores stay coalesced
#pragma unroll
                for (int mi = 0; mi < 4; ++mi)
#pragma unroll
                    for (int ni = 0; ni < 4; ++ni)
                        acc[mi][ni] = __builtin_amdgcn_mfma_f32_16x16x32_bf16(
                            bF[ni], aF[mi], acc[mi][ni], 0, 0, 0);
            } else {
#pragma unroll
                for (int mi = 0; mi < 4; ++mi)
#pragma unroll
                    for (int ni = 0; ni < 4; ++ni)
                        acc[mi][ni] = __builtin_amdgcn_mfma_f32_16x16x32_bf16(
                            aF[mi], bF[ni], acc[mi][ni], 0, 0, 0);
            }
        }
        __syncthreads();
    }
    const size_t WSZ = (size_t)BHT * SEQ * HD;
    if (wsel == 2) {
#pragma unroll
        for (int mi = 0; mi < 4; ++mi)
#pragma unroll
            for (int ni = 0; ni < 4; ++ni)
#pragma unroll
                for (int r = 0; r < 4; ++r) {
                    int m  = m0 + wm * 64 + mi * 16 + r16;
                    int nn = n0 + wn * 64 + ni * 16 + quad * 4 + r;
                    int b = m >> 12, s = m & 4095;
                    int hh = nn >> 6, dd = nn & 63;
                    qkv[2 * WSZ + (((size_t)b * NH + hh) * HD + dd) * SEQ + s] =
                        f2bf(acc[mi][ni][r]);
                }
    } else {
        const float sc = (wsel == 0) ? C2 : 1.0f;
#pragma unroll
        for (int mi = 0; mi < 4; ++mi)
#pragma unroll
            for (int ni = 0; ni < 4; ++ni)
#pragma unroll
                for (int r = 0; r < 4; ++r) {
                    int m = m0 + wm * 64 + mi * 16 + quad * 4 + r;
                    int b = m >> 12, s = m & 4095;
                    int nn = n0 + wn * 64 + ni * 16 + r16;
                    int hh = nn >> 6, dd = nn & 63;
                    size_t off = (((size_t)b * NH + hh) * SEQ + s) * HD + dd;
                    qkv[(size_t)wsel * WSZ + off] = f2bf(acc[mi][ni][r] * sc);
                }
    }
}

// ---------------------------------------------------------------------------
// Kernel 2: flash attention, 32x32x16 MFMA, fixed-max softmax, Q pre-scaled.
// Round-12: REVERT to the round-1 kernel verbatim — the measured best
// (148.6us). All structural variants are now measured and closed:
// split-K (r4, occupancy quantization), 48KB pipeline (r5, 2 blocks/CU),
// V-direct (r6, uncoalesced), 4-chain ILP (r7, spills), counted-vmcnt
// (r8, neutral), QK-ahead software pipeline (r11, occupancy loss).
// This decomposition's flash plateau is ~148us.
// ---------------------------------------------------------------------------
__global__ __launch_bounds__(256) void flash_attn(
    const unsigned short* __restrict__ qkv, const float* __restrict__ mask,
    unsigned short* __restrict__ ctx) {
    __shared__ __align__(16) unsigned short Ksm[2][64 * 64];   // [key][dim], swizzled
    __shared__ __align__(16) unsigned short Vtsm[2][64 * 64];  // [dim][key], swizzled
    __shared__ __align__(16) unsigned short Mall[SEQ];         // log2-domain bf16 mask
    const int t  = threadIdx.x;
    const int bh = blockIdx.y;
    const int b  = bh / NH;
    const int h  = bh % NH;
    const int qbase = blockIdx.x * 128;
    const size_t WSZ = (size_t)BHT * SEQ * HD;
    const unsigned short* Qp = qkv + (size_t)bh * SEQ * HD;
    const unsigned short* Kp = Qp + WSZ;
    const unsigned short* Vt = qkv + 2 * WSZ + (size_t)bh * HD * SEQ;
    const int w = t >> 6, lane = t & 63, n31 = lane & 31, hi = lane >> 5;
    const int lrow = lane >> 3;
    const int lchs = ((lane & 7) ^ (lrow & 7)) * 8;

    bf16x8 qF[4];
    {
        int qrow = qbase + w * 32 + n31;
#pragma unroll
        for (int kc = 0; kc < 4; ++kc)
            qF[kc] = *(const bf16x8*)&Qp[(size_t)qrow * HD + kc * 16 + hi * 8];
    }
    bf16x8 bOnes = {};
    if (hi == 0) bOnes[0] = (short)0x3F80;   // 1.0 at k==0

    // one-time: whole mask row for this batch -> LDS, log2 domain, bf16
#pragma unroll
    for (int i = 0; i < 4; ++i) {
        float4 mv = ((const float4*)(mask + (size_t)b * SEQ))[i * 256 + t];
        ushort4 o;
        o.x = f2bf(LOG2E * mv.x); o.y = f2bf(LOG2E * mv.y);
        o.z = f2bf(LOG2E * mv.z); o.w = f2bf(LOG2E * mv.w);
        *(ushort4*)&Mall[(i * 256 + t) * 4] = o;
    }

    // prologue: stage tile 0 into buffer 0
#pragma unroll
    for (int i = 0; i < 2; ++i) {
        int row = w * 16 + i * 8;
        cp16(&Kp[(size_t)(row + lrow) * HD + lchs], &Ksm[0][row * 64]);
        cp16(&Vt[(size_t)(row + lrow) * SEQ + lchs], &Vtsm[0][row * 64]);
    }
    __syncthreads();

    f32x16 oAcc[2] = {};
    float l_i = 0.0f;
    const int sw = n31 & 7;                  // row-swizzle for frag reads
    int cur = 0;

    for (int kt = 0; kt < SEQ / 64; ++kt) {
        // issue next-tile loads first: they fly during this tile's compute
        if (kt + 1 < SEQ / 64) {
#pragma unroll
            for (int i = 0; i < 2; ++i) {
                int row = w * 16 + i * 8;
                cp16(&Kp[(size_t)((kt + 1) * 64 + row + lrow) * HD + lchs],
                     &Ksm[cur ^ 1][row * 64]);
                cp16(&Vt[(size_t)(row + lrow) * SEQ + (kt + 1) * 64 + lchs],
                     &Vtsm[cur ^ 1][row * 64]);
            }
        }

        // S^T = K Q^T (log2 domain) + mask via MFMA C-init
        float p[2][16];
        float rs0 = 0.f, rs1 = 0.f, rs2 = 0.f, rs3 = 0.f;
#pragma unroll
        for (int st = 0; st < 2; ++st) {
            bf16x8 am = {};
            {
                unsigned short mv = Mall[kt * 64 + st * 32 + n31];
                am[0] = (hi == 0) ? (short)mv : (short)0;
            }
            f32x16 sA = {};
            sA = __builtin_amdgcn_mfma_f32_32x32x16_bf16(am, bOnes, sA, 0, 0, 0);
            __builtin_amdgcn_s_setprio(1);
#pragma unroll
            for (int kc = 0; kc < 4; ++kc) {
                bf16x8 kF = *(const bf16x8*)
                    &Ksm[cur][(st * 32 + n31) * 64 + (((2 * kc + hi) ^ sw) * 8)];
                sA = __builtin_amdgcn_mfma_f32_32x32x16_bf16(kF, qF[kc], sA, 0, 0, 0);
            }
            __builtin_amdgcn_s_setprio(0);
#pragma unroll
            for (int r = 0; r < 16; ++r) p[st][r] = __builtin_amdgcn_exp2f(sA[r]);
            rs0 += p[st][0] + p[st][4] + p[st][8]  + p[st][12];
            rs1 += p[st][1] + p[st][5] + p[st][9]  + p[st][13];
            rs2 += p[st][2] + p[st][6] + p[st][10] + p[st][14];
            rs3 += p[st][3] + p[st][7] + p[st][11] + p[st][15];
        }
        l_i += (rs0 + rs1) + (rs2 + rs3);

        // P -> PV B-fragments fully in-register (T12).
        // p[st][r] = P[q=n31][key = st*32 + (r&3)+8*(r>>2)+4*hi].
        bf16x8 pF[4];
#pragma unroll
        for (int st = 0; st < 2; ++st) {
            uint32_t pw[8];
#pragma unroll
            for (int i = 0; i < 8; ++i)
                pw[i] = cvtpk(p[st][2 * i], p[st][2 * i + 1]);
#pragma unroll
            for (int half = 0; half < 2; ++half) {
                auto r02 = __builtin_amdgcn_permlane32_swap(
                    pw[half * 4 + 0], pw[half * 4 + 2], false, false);
                auto r13 = __builtin_amdgcn_permlane32_swap(
                    pw[half * 4 + 1], pw[half * 4 + 3], false, false);
                union { u32x4 u; bf16x8 h; } f;
                f.u[0] = r02[0]; f.u[1] = r13[0]; f.u[2] = r02[1]; f.u[3] = r13[1];
                pF[st * 2 + half] = f.h;
            }
        }

        // O^T += V^T P^T
        __builtin_amdgcn_s_setprio(1);
#pragma unroll
        for (int kc = 0; kc < 4; ++kc) {
            bf16x8 pFk = pF[kc];
#pragma unroll
            for (int dt = 0; dt < 2; ++dt) {
                bf16x8 vF = *(const bf16x8*)
                    &Vtsm[cur][(dt * 32 + n31) * 64 + (((2 * kc + hi) ^ sw) * 8)];
                oAcc[dt] = __builtin_amdgcn_mfma_f32_32x32x16_bf16(vF, pFk, oAcc[dt], 0, 0, 0);
            }
        }
        __builtin_amdgcn_s_setprio(0);

        __syncthreads();   // drains vmcnt: next tile staged; buffer flip safe
        cur ^= 1;
    }
    l_i += __shfl_xor(l_i, 32);
    float inv = 1.0f / l_i;
    int s = qbase + w * 32 + n31;
    unsigned short* obase = &ctx[((size_t)b * SEQ + s) * ED + h * HD];
#pragma unroll
    for (int dt = 0; dt < 2; ++dt)
#pragma unroll
        for (int g = 0; g < 4; ++g) {
            ushort4 o;
            o.x = f2bf(oAcc[dt][4 * g + 0] * inv);
            o.y = f2bf(oAcc[dt][4 * g + 1] * inv);
            o.z = f2bf(oAcc[dt][4 * g + 2] * inv);
            o.w = f2bf(oAcc[dt][4 * g + 3] * inv);
            *(ushort4*)&obase[dt * 32 + hi * 4 + 8 * g] = o;
        }
}

// ---------------------------------------------------------------------------
// Kernel 3: output projection, 128x128 tile m97-style.
// Round-12: + bijective XCD swizzle (T1). Grid 6x64 = 384 blocks, 384%8==0:
// swz = (lin&7)*48 + (lin>>3): each XCD gets 48 contiguous tiles = 8 full
// M-rows of 6 N-tiles (A panels XCD-local; Wo 1.1MB fits every L2 anyway).
// out[m][n] = sum_k ctx[m][k]*Wo[n][k] + bo[n], fp32 output.
// ---------------------------------------------------------------------------
__global__ __launch_bounds__(256) void out_gemm(
    const unsigned short* __restrict__ Ab,   // ctx bf16 [8192][768]
    const unsigned short* __restrict__ Wob,  // [768][768] bf16
    const float* __restrict__ bo, float* __restrict__ out) {
    __shared__ __align__(16) unsigned short Ah[128 * 64];
    __shared__ __align__(16) unsigned short Bh[128 * 64];
    const int t = threadIdx.x, w = t >> 6, lane = t & 63;
    const int quad = lane >> 4, r16 = lane & 15;
    const int wm = w >> 1, wn = w & 1;
    // XCD-aware bijective remap (nwg=384, nwg%8==0)
    const int lin = blockIdx.y * 6 + blockIdx.x;
    const int swz = (lin & 7) * 48 + (lin >> 3);
    const int bx = swz % 6, by = swz / 6;
    const int m0 = by * 128, n0 = bx * 128;
    const int lrow = lane >> 3;
    const int lchs = ((lane & 7) ^ (lrow & 7)) * 8;

    f32x4 acc[4][4] = {};
    for (int kt = 0; kt < ED / 64; ++kt) {
        const int k0 = kt * 64;
#pragma unroll
        for (int i = 0; i < 4; ++i) {
            int row = i * 32 + w * 8;
            cp16(&Ab[(size_t)(m0 + row + lrow) * ED + k0 + lchs], &Ah[row * 64]);
            cp16(&Wob[(size_t)(n0 + row + lrow) * ED + k0 + lchs], &Bh[row * 64]);
        }
        __syncthreads();
#pragma unroll
        for (int kk = 0; kk < 2; ++kk) {
            bf16x8 aF[4], bF[4];
#pragma unroll
            for (int mi = 0; mi < 4; ++mi) {
                int R = wm * 64 + mi * 16 + r16;
                aF[mi] = *(const bf16x8*)&Ah[R * 64 + (((kk * 4 + quad) ^ (r16 & 7)) * 8)];
            }
#pragma unroll
            for (int ni = 0; ni < 4; ++ni) {
                int R = wn * 64 + ni * 16 + r16;
                bF[ni] = *(const bf16x8*)&Bh[R * 64 + (((kk * 4 + quad) ^ (r16 & 7)) * 8)];
            }
#pragma unroll
            for (int mi = 0; mi < 4; ++mi)
#pragma unroll
                for (int ni = 0; ni < 4; ++ni)
                    acc[mi][ni] = __builtin_amdgcn_mfma_f32_16x16x32_bf16(
                        aF[mi], bF[ni], acc[mi][ni], 0, 0, 0);
        }
        __syncthreads();
    }
    float bov[4];
#pragma unroll
    for (int ni = 0; ni < 4; ++ni) bov[ni] = bo[n0 + wn * 64 + ni * 16 + r16];
#pragma unroll
    for (int mi = 0; mi < 4; ++mi)
#pragma unroll
        for (int ni = 0; ni < 4; ++ni)
#pragma unroll
            for (int r = 0; r < 4; ++r) {
                int m = m0 + wm * 64 + mi * 16 + quad * 4 + r;
                int n = n0 + wn * 64 + ni * 16 + r16;
                out[(size_t)m * ED + n] = acc[mi][ni][r] + bov[ni];
            }
}

// ---------------------------------------------------------------------------
extern "C" void kernel_launch(void* const* d_in, const int* in_sizes, int n_in,
                              void* d_out, int out_size, void* d_ws, size_t ws_size,
                              hipStream_t stream) {
    const float* H    = (const float*)d_in[0];
    const float* mask = (const float*)d_in[1];
    const float* Wq   = (const float*)d_in[2];
    const float* Wk   = (const float*)d_in[3];
    const float* Wv   = (const float*)d_in[4];
    const float* Wo   = (const float*)d_in[5];
    const float* bo   = (const float*)d_in[6];
    unsigned short* ws = (unsigned short*)d_ws;
    const size_t WSZ = (size_t)BHT * SEQ * HD;
    unsigned short* qkv = ws;                           // 3*WSZ bf16
    unsigned short* ctx = ws + 3 * WSZ;                 // [8192][768] bf16
    unsigned short* WoB = ctx + (size_t)MTOT * ED;      // [768][768] bf16
    float* out = (float*)d_out;
    // d_out doubles as scratch for bf16 H and Wqkv until out_gemm overwrites it
    unsigned short* Hb = (unsigned short*)d_out;        // 6291456 elems
    unsigned short* Wb = Hb + (size_t)MTOT * ED;        // 1769472 elems

    convert_bf16<<<CVT_TOTAL / 256, 256, 0, stream>>>(H, Wq, Wk, Wv, Wo, Hb, WoB);
    qkv_gemm<<<dim3(3 * ED / 128, MTOT / 128), 256, 0, stream>>>(Hb, Wb, qkv);
    flash_attn<<<dim3(SEQ / 128, BHT), 256, 0, stream>>>(qkv, mask, ctx);
    out_gemm<<<dim3(ED / 128, MTOT / 128), 256, 0, stream>>>(ctx, WoB, bo, out);
}

// Round 13
// 285.226 us; speedup vs baseline: 1.1164x; 1.0110x over previous
//
#include <hip/hip_runtime.h>
#include <stdint.h>

#define ED   768
#define NH   12
#define HD   64
#define SEQ  4096
#define BSZ  2
#define BHT  (BSZ*NH)          // 24
#define MTOT (BSZ*SEQ)         // 8192

typedef short bf16x8  __attribute__((ext_vector_type(8)));   // 8 bf16 (4 VGPRs)
typedef float f32x4   __attribute__((ext_vector_type(4)));
typedef float f32x16  __attribute__((ext_vector_type(16)));
typedef unsigned int u32x4 __attribute__((ext_vector_type(4)));

#define LOG2E 1.44269504088896340736f
#define C2    (0.125f * LOG2E)   // folded into Q at projection time

// fp32 -> bf16 round-to-nearest-even
__device__ __forceinline__ unsigned short f2bf(float f) {
    union { float f; uint32_t u; } v; v.f = f;
    uint32_t u = v.u;
    u += 0x7fffu + ((u >> 16) & 1u);
    return (unsigned short)(u >> 16);
}

// pack two f32 -> one u32 holding 2 bf16 (lo = first arg)
__device__ __forceinline__ uint32_t cvtpk(float lo, float hi) {
    uint32_t r;
    asm("v_cvt_pk_bf16_f32 %0, %1, %2" : "=v"(r) : "v"(lo), "v"(hi));
    return r;
}

// async global->LDS, 16B/lane; lds dst = wave-uniform base, lands at base+lane*16
__device__ __forceinline__ void cp16(const unsigned short* g, unsigned short* l) {
    __builtin_amdgcn_global_load_lds(
        (const __attribute__((address_space(1))) unsigned int*)(const void*)g,
        (__attribute__((address_space(3))) unsigned int*)(void*)l,
        16, 0, 0);
}
// XOR-swizzle: LDS 16B-chunk slot c of row r holds global chunk c^(r&7).
// Staging: lane fetches global chunk (lane&7)^(lrow&7); reads use chunk^(row&7).

// ---------------------------------------------------------------------------
// Kernel 0: one-time fp32->bf16 convert. H,Wq|Wk|Wv -> d_out scratch (dead
// until out_gemm writes); Wo -> WoB in d_ws.
// ---------------------------------------------------------------------------
#define H_CHUNKS  (MTOT * ED / 4)            // 1572864 float4s
#define W_CHUNKS  (ED * ED / 4)              // 147456 per weight
#define CVT_TOTAL (H_CHUNKS + 4 * W_CHUNKS)  // 2162688 = 8448 * 256

__global__ __launch_bounds__(256) void convert_bf16(
    const float* __restrict__ H,  const float* __restrict__ Wq,
    const float* __restrict__ Wk, const float* __restrict__ Wv,
    const float* __restrict__ Wo, unsigned short* __restrict__ dst,
    unsigned short* __restrict__ WoB) {
    int i4 = blockIdx.x * 256 + threadIdx.x;
    float4 v;
    ushort4* optr;
    if (i4 < H_CHUNKS) { v = ((const float4*)H)[i4]; optr = (ushort4*)dst + i4; }
    else {
        int j = i4 - H_CHUNKS;
        if (j < 3 * W_CHUNKS) {
            if (j < W_CHUNKS)          v = ((const float4*)Wq)[j];
            else if (j < 2 * W_CHUNKS) v = ((const float4*)Wk)[j - W_CHUNKS];
            else                       v = ((const float4*)Wv)[j - 2 * W_CHUNKS];
            optr = (ushort4*)dst + i4;
        } else {
            v = ((const float4*)Wo)[j - 3 * W_CHUNKS];
            optr = (ushort4*)WoB + (j - 3 * W_CHUNKS);
        }
    }
    ushort4 o;
    o.x = f2bf(v.x); o.y = f2bf(v.y); o.z = f2bf(v.z); o.w = f2bf(v.w);
    *optr = o;
}

// ---------------------------------------------------------------------------
// Kernel 1: QKV projection, 128x128 tile, BK=64, global_load_lds + XOR swizzle.
// Bijective XCD swizzle (T1): grid 18x64 = 1152, 1152%8==0.
// Q written pre-scaled by C2.  Q,K -> [b][h][s][d];  V -> [b][h][d][s].
// ---------------------------------------------------------------------------
__global__ __launch_bounds__(256) void qkv_gemm(
    const unsigned short* __restrict__ Hb,   // [8192][768] bf16
    const unsigned short* __restrict__ Wb,   // [2304][768] bf16 (Wq|Wk|Wv)
    unsigned short* __restrict__ qkv) {
    __shared__ __align__(16) unsigned short Ah[128 * 64];
    __shared__ __align__(16) unsigned short Bh[128 * 64];
    const int t = threadIdx.x, w = t >> 6, lane = t & 63;
    const int quad = lane >> 4, r16 = lane & 15;
    const int wm = w >> 1, wn = w & 1;
    // XCD-aware bijective remap (nwg=1152, nwg%8==0)
    const int lin = blockIdx.y * 18 + blockIdx.x;
    const int swz = (lin & 7) * 144 + (lin >> 3);
    const int bx = swz % 18, by = swz / 18;
    const int m0 = by * 128, n0g = bx * 128;
    const int wsel = n0g / ED, n0 = n0g % ED;
    const int lrow = lane >> 3;
    const int lchs = ((lane & 7) ^ (lrow & 7)) * 8;   // swizzled source chunk

    f32x4 acc[4][4] = {};
    for (int kt = 0; kt < ED / 64; ++kt) {
        const int k0 = kt * 64;
#pragma unroll
        for (int i = 0; i < 4; ++i) {
            int row = i * 32 + w * 8;
            cp16(&Hb[(size_t)(m0 + row + lrow) * ED + k0 + lchs], &Ah[row * 64]);
            cp16(&Wb[(size_t)(n0g + row + lrow) * ED + k0 + lchs], &Bh[row * 64]);
        }
        __syncthreads();
#pragma unroll
        for (int kk = 0; kk < 2; ++kk) {
            bf16x8 aF[4], bF[4];
#pragma unroll
            for (int mi = 0; mi < 4; ++mi) {
                int R = wm * 64 + mi * 16 + r16;
                aF[mi] = *(const bf16x8*)&Ah[R * 64 + (((kk * 4 + quad) ^ (r16 & 7)) * 8)];
            }
#pragma unroll
            for (int ni = 0; ni < 4; ++ni) {
                int R = wn * 64 + ni * 16 + r16;
                bF[ni] = *(const bf16x8*)&Bh[R * 64 + (((kk * 4 + quad) ^ (r16 & 7)) * 8)];
            }
            if (wsel == 2) {   // V: compute C^T so V^T stores stay coalesced
#pragma unroll
                for (int mi = 0; mi < 4; ++mi)
#pragma unroll
                    for (int ni = 0; ni < 4; ++ni)
                        acc[mi][ni] = __builtin_amdgcn_mfma_f32_16x16x32_bf16(
                            bF[ni], aF[mi], acc[mi][ni], 0, 0, 0);
            } else {
#pragma unroll
                for (int mi = 0; mi < 4; ++mi)
#pragma unroll
                    for (int ni = 0; ni < 4; ++ni)
                        acc[mi][ni] = __builtin_amdgcn_mfma_f32_16x16x32_bf16(
                            aF[mi], bF[ni], acc[mi][ni], 0, 0, 0);
            }
        }
        __syncthreads();
    }
    const size_t WSZ = (size_t)BHT * SEQ * HD;
    if (wsel == 2) {
#pragma unroll
        for (int mi = 0; mi < 4; ++mi)
#pragma unroll
            for (int ni = 0; ni < 4; ++ni)
#pragma unroll
                for (int r = 0; r < 4; ++r) {
                    int m  = m0 + wm * 64 + mi * 16 + r16;
                    int nn = n0 + wn * 64 + ni * 16 + quad * 4 + r;
                    int b = m >> 12, s = m & 4095;
                    int hh = nn >> 6, dd = nn & 63;
                    qkv[2 * WSZ + (((size_t)b * NH + hh) * HD + dd) * SEQ + s] =
                        f2bf(acc[mi][ni][r]);
                }
    } else {
        const float sc = (wsel == 0) ? C2 : 1.0f;
#pragma unroll
        for (int mi = 0; mi < 4; ++mi)
#pragma unroll
            for (int ni = 0; ni < 4; ++ni)
#pragma unroll
                for (int r = 0; r < 4; ++r) {
                    int m = m0 + wm * 64 + mi * 16 + quad * 4 + r;
                    int b = m >> 12, s = m & 4095;
                    int nn = n0 + wn * 64 + ni * 16 + r16;
                    int hh = nn >> 6, dd = nn & 63;
                    size_t off = (((size_t)b * NH + hh) * SEQ + s) * HD + dd;
                    qkv[(size_t)wsel * WSZ + off] = f2bf(acc[mi][ni][r] * sc);
                }
    }
}

// ---------------------------------------------------------------------------
// Kernel 2: flash attention — round-1 body verbatim (measured best, 148.0us;
// plateau confirmed across r4-r11 structural variants, all closed).
// ---------------------------------------------------------------------------
__global__ __launch_bounds__(256) void flash_attn(
    const unsigned short* __restrict__ qkv, const float* __restrict__ mask,
    unsigned short* __restrict__ ctx) {
    __shared__ __align__(16) unsigned short Ksm[2][64 * 64];   // [key][dim], swizzled
    __shared__ __align__(16) unsigned short Vtsm[2][64 * 64];  // [dim][key], swizzled
    __shared__ __align__(16) unsigned short Mall[SEQ];         // log2-domain bf16 mask
    const int t  = threadIdx.x;
    const int bh = blockIdx.y;
    const int b  = bh / NH;
    const int h  = bh % NH;
    const int qbase = blockIdx.x * 128;
    const size_t WSZ = (size_t)BHT * SEQ * HD;
    const unsigned short* Qp = qkv + (size_t)bh * SEQ * HD;
    const unsigned short* Kp = Qp + WSZ;
    const unsigned short* Vt = qkv + 2 * WSZ + (size_t)bh * HD * SEQ;
    const int w = t >> 6, lane = t & 63, n31 = lane & 31, hi = lane >> 5;
    const int lrow = lane >> 3;
    const int lchs = ((lane & 7) ^ (lrow & 7)) * 8;

    bf16x8 qF[4];
    {
        int qrow = qbase + w * 32 + n31;
#pragma unroll
        for (int kc = 0; kc < 4; ++kc)
            qF[kc] = *(const bf16x8*)&Qp[(size_t)qrow * HD + kc * 16 + hi * 8];
    }
    bf16x8 bOnes = {};
    if (hi == 0) bOnes[0] = (short)0x3F80;   // 1.0 at k==0

    // one-time: whole mask row for this batch -> LDS, log2 domain, bf16
#pragma unroll
    for (int i = 0; i < 4; ++i) {
        float4 mv = ((const float4*)(mask + (size_t)b * SEQ))[i * 256 + t];
        ushort4 o;
        o.x = f2bf(LOG2E * mv.x); o.y = f2bf(LOG2E * mv.y);
        o.z = f2bf(LOG2E * mv.z); o.w = f2bf(LOG2E * mv.w);
        *(ushort4*)&Mall[(i * 256 + t) * 4] = o;
    }

    // prologue: stage tile 0 into buffer 0
#pragma unroll
    for (int i = 0; i < 2; ++i) {
        int row = w * 16 + i * 8;
        cp16(&Kp[(size_t)(row + lrow) * HD + lchs], &Ksm[0][row * 64]);
        cp16(&Vt[(size_t)(row + lrow) * SEQ + lchs], &Vtsm[0][row * 64]);
    }
    __syncthreads();

    f32x16 oAcc[2] = {};
    float l_i = 0.0f;
    const int sw = n31 & 7;                  // row-swizzle for frag reads
    int cur = 0;

    for (int kt = 0; kt < SEQ / 64; ++kt) {
        // issue next-tile loads first: they fly during this tile's compute
        if (kt + 1 < SEQ / 64) {
#pragma unroll
            for (int i = 0; i < 2; ++i) {
                int row = w * 16 + i * 8;
                cp16(&Kp[(size_t)((kt + 1) * 64 + row + lrow) * HD + lchs],
                     &Ksm[cur ^ 1][row * 64]);
                cp16(&Vt[(size_t)(row + lrow) * SEQ + (kt + 1) * 64 + lchs],
                     &Vtsm[cur ^ 1][row * 64]);
            }
        }

        // S^T = K Q^T (log2 domain) + mask via MFMA C-init
        float p[2][16];
        float rs0 = 0.f, rs1 = 0.f, rs2 = 0.f, rs3 = 0.f;
#pragma unroll
        for (int st = 0; st < 2; ++st) {
            bf16x8 am = {};
            {
                unsigned short mv = Mall[kt * 64 + st * 32 + n31];
                am[0] = (hi == 0) ? (short)mv : (short)0;
            }
            f32x16 sA = {};
            sA = __builtin_amdgcn_mfma_f32_32x32x16_bf16(am, bOnes, sA, 0, 0, 0);
            __builtin_amdgcn_s_setprio(1);
#pragma unroll
            for (int kc = 0; kc < 4; ++kc) {
                bf16x8 kF = *(const bf16x8*)
                    &Ksm[cur][(st * 32 + n31) * 64 + (((2 * kc + hi) ^ sw) * 8)];
                sA = __builtin_amdgcn_mfma_f32_32x32x16_bf16(kF, qF[kc], sA, 0, 0, 0);
            }
            __builtin_amdgcn_s_setprio(0);
#pragma unroll
            for (int r = 0; r < 16; ++r) p[st][r] = __builtin_amdgcn_exp2f(sA[r]);
            rs0 += p[st][0] + p[st][4] + p[st][8]  + p[st][12];
            rs1 += p[st][1] + p[st][5] + p[st][9]  + p[st][13];
            rs2 += p[st][2] + p[st][6] + p[st][10] + p[st][14];
            rs3 += p[st][3] + p[st][7] + p[st][11] + p[st][15];
        }
        l_i += (rs0 + rs1) + (rs2 + rs3);

        // P -> PV B-fragments fully in-register (T12).
        // p[st][r] = P[q=n31][key = st*32 + (r&3)+8*(r>>2)+4*hi].
        bf16x8 pF[4];
#pragma unroll
        for (int st = 0; st < 2; ++st) {
            uint32_t pw[8];
#pragma unroll
            for (int i = 0; i < 8; ++i)
                pw[i] = cvtpk(p[st][2 * i], p[st][2 * i + 1]);
#pragma unroll
            for (int half = 0; half < 2; ++half) {
                auto r02 = __builtin_amdgcn_permlane32_swap(
                    pw[half * 4 + 0], pw[half * 4 + 2], false, false);
                auto r13 = __builtin_amdgcn_permlane32_swap(
                    pw[half * 4 + 1], pw[half * 4 + 3], false, false);
                union { u32x4 u; bf16x8 h; } f;
                f.u[0] = r02[0]; f.u[1] = r13[0]; f.u[2] = r02[1]; f.u[3] = r13[1];
                pF[st * 2 + half] = f.h;
            }
        }

        // O^T += V^T P^T
        __builtin_amdgcn_s_setprio(1);
#pragma unroll
        for (int kc = 0; kc < 4; ++kc) {
            bf16x8 pFk = pF[kc];
#pragma unroll
            for (int dt = 0; dt < 2; ++dt) {
                bf16x8 vF = *(const bf16x8*)
                    &Vtsm[cur][(dt * 32 + n31) * 64 + (((2 * kc + hi) ^ sw) * 8)];
                oAcc[dt] = __builtin_amdgcn_mfma_f32_32x32x16_bf16(vF, pFk, oAcc[dt], 0, 0, 0);
            }
        }
        __builtin_amdgcn_s_setprio(0);

        __syncthreads();   // drains vmcnt: next tile staged; buffer flip safe
        cur ^= 1;
    }
    l_i += __shfl_xor(l_i, 32);
    float inv = 1.0f / l_i;
    int s = qbase + w * 32 + n31;
    unsigned short* obase = &ctx[((size_t)b * SEQ + s) * ED + h * HD];
#pragma unroll
    for (int dt = 0; dt < 2; ++dt)
#pragma unroll
        for (int g = 0; g < 4; ++g) {
            ushort4 o;
            o.x = f2bf(oAcc[dt][4 * g + 0] * inv);
            o.y = f2bf(oAcc[dt][4 * g + 1] * inv);
            o.z = f2bf(oAcc[dt][4 * g + 2] * inv);
            o.w = f2bf(oAcc[dt][4 * g + 3] * inv);
            *(ushort4*)&obase[dt * 32 + hi * 4 + 8 * g] = o;
        }
}

// ---------------------------------------------------------------------------
// Kernel 3: output projection. Round-13: 64x128 tiles -> 768 blocks (~3
// blocks/CU) fixing the 384-block (1.5/CU) occupancy shortfall. Each wave:
// 32x64 output via acc[2][4]; LDS 24KB (A 8KB + B 16KB). Inner loop and
// staging pattern otherwise identical to the verified 128x128 kernel.
// Bijective XCD swizzle kept (768%8==0): each XCD gets 96 contiguous tiles
// = 16 M-rows x 6 N-tiles -> A panels XCD-local.
// out[m][n] = sum_k ctx[m][k]*Wo[n][k] + bo[n], fp32 output.
// ---------------------------------------------------------------------------
__global__ __launch_bounds__(256) void out_gemm(
    const unsigned short* __restrict__ Ab,   // ctx bf16 [8192][768]
    const unsigned short* __restrict__ Wob,  // [768][768] bf16
    const float* __restrict__ bo, float* __restrict__ out) {
    __shared__ __align__(16) unsigned short Ah[64 * 64];     // 8KB
    __shared__ __align__(16) unsigned short Bh[128 * 64];    // 16KB
    const int t = threadIdx.x, w = t >> 6, lane = t & 63;
    const int quad = lane >> 4, r16 = lane & 15;
    const int wm = w & 1, wn = w >> 1;       // 2 M-halves x 2 N-halves
    // XCD-aware bijective remap (nwg=768, nwg%8==0)
    const int lin = blockIdx.y * 6 + blockIdx.x;
    const int swz = (lin & 7) * 96 + (lin >> 3);
    const int bx = swz % 6, by = swz / 6;
    const int m0 = by * 64, n0 = bx * 128;
    const int lrow = lane >> 3;
    const int lchs = ((lane & 7) ^ (lrow & 7)) * 8;

    f32x4 acc[2][4] = {};
    for (int kt = 0; kt < ED / 64; ++kt) {
        const int k0 = kt * 64;
#pragma unroll
        for (int i = 0; i < 2; ++i) {        // A: 64 rows
            int row = i * 32 + w * 8;
            cp16(&Ab[(size_t)(m0 + row + lrow) * ED + k0 + lchs], &Ah[row * 64]);
        }
#pragma unroll
        for (int i = 0; i < 4; ++i) {        // B: 128 rows
            int row = i * 32 + w * 8;
            cp16(&Wob[(size_t)(n0 + row + lrow) * ED + k0 + lchs], &Bh[row * 64]);
        }
        __syncthreads();
#pragma unroll
        for (int kk = 0; kk < 2; ++kk) {
            bf16x8 aF[2], bF[4];
#pragma unroll
            for (int mi = 0; mi < 2; ++mi) {
                int R = wm * 32 + mi * 16 + r16;
                aF[mi] = *(const bf16x8*)&Ah[R * 64 + (((kk * 4 + quad) ^ (r16 & 7)) * 8)];
            }
#pragma unroll
            for (int ni = 0; ni < 4; ++ni) {
                int R = wn * 64 + ni * 16 + r16;
                bF[ni] = *(const bf16x8*)&Bh[R * 64 + (((kk * 4 + quad) ^ (r16 & 7)) * 8)];
            }
#pragma unroll
            for (int mi = 0; mi < 2; ++mi)
#pragma unroll
                for (int ni = 0; ni < 4; ++ni)
                    acc[mi][ni] = __builtin_amdgcn_mfma_f32_16x16x32_bf16(
                        aF[mi], bF[ni], acc[mi][ni], 0, 0, 0);
        }
        __syncthreads();
    }
    float bov[4];
#pragma unroll
    for (int ni = 0; ni < 4; ++ni) bov[ni] = bo[n0 + wn * 64 + ni * 16 + r16];
#pragma unroll
    for (int mi = 0; mi < 2; ++mi)
#pragma unroll
        for (int ni = 0; ni < 4; ++ni)
#pragma unroll
            for (int r = 0; r < 4; ++r) {
                int m = m0 + wm * 32 + mi * 16 + quad * 4 + r;
                int n = n0 + wn * 64 + ni * 16 + r16;
                out[(size_t)m * ED + n] = acc[mi][ni][r] + bov[ni];
            }
}

// ---------------------------------------------------------------------------
extern "C" void kernel_launch(void* const* d_in, const int* in_sizes, int n_in,
                              void* d_out, int out_size, void* d_ws, size_t ws_size,
                              hipStream_t stream) {
    const float* H    = (const float*)d_in[0];
    const float* mask = (const float*)d_in[1];
    const float* Wq   = (const float*)d_in[2];
    const float* Wk   = (const float*)d_in[3];
    const float* Wv   = (const float*)d_in[4];
    const float* Wo   = (const float*)d_in[5];
    const float* bo   = (const float*)d_in[6];
    unsigned short* ws = (unsigned short*)d_ws;
    const size_t WSZ = (size_t)BHT * SEQ * HD;
    unsigned short* qkv = ws;                           // 3*WSZ bf16
    unsigned short* ctx = ws + 3 * WSZ;                 // [8192][768] bf16
    unsigned short* WoB = ctx + (size_t)MTOT * ED;      // [768][768] bf16
    float* out = (float*)d_out;
    // d_out doubles as scratch for bf16 H and Wqkv until out_gemm overwrites it
    unsigned short* Hb = (unsigned short*)d_out;        // 6291456 elems
    unsigned short* Wb = Hb + (size_t)MTOT * ED;        // 1769472 elems

    convert_bf16<<<CVT_TOTAL / 256, 256, 0, stream>>>(H, Wq, Wk, Wv, Wo, Hb, WoB);
    qkv_gemm<<<dim3(3 * ED / 128, MTOT / 128), 256, 0, stream>>>(Hb, Wb, qkv);
    flash_attn<<<dim3(SEQ / 128, BHT), 256, 0, stream>>>(qkv, mask, ctx);
    out_gemm<<<dim3(ED / 128, MTOT / 64), 256, 0, stream>>>(ctx, WoB, bo, out);
}

// Round 14
// 279.727 us; speedup vs baseline: 1.1383x; 1.0197x over previous
//
#include <hip/hip_runtime.h>
#include <stdint.h>

#define ED   768
#define NH   12
#define HD   64
#define SEQ  4096
#define BSZ  2
#define BHT  (BSZ*NH)          // 24
#define MTOT (BSZ*SEQ)         // 8192

typedef short bf16x8  __attribute__((ext_vector_type(8)));   // 8 bf16 (4 VGPRs)
typedef float f32x4   __attribute__((ext_vector_type(4)));
typedef float f32x16  __attribute__((ext_vector_type(16)));
typedef unsigned int u32x4 __attribute__((ext_vector_type(4)));

#define LOG2E 1.44269504088896340736f
#define C2    (0.125f * LOG2E)   // folded into Q at projection time

// fp32 -> bf16 round-to-nearest-even
__device__ __forceinline__ unsigned short f2bf(float f) {
    union { float f; uint32_t u; } v; v.f = f;
    uint32_t u = v.u;
    u += 0x7fffu + ((u >> 16) & 1u);
    return (unsigned short)(u >> 16);
}

// pack two f32 -> one u32 holding 2 bf16 (lo = first arg)
__device__ __forceinline__ uint32_t cvtpk(float lo, float hi) {
    uint32_t r;
    asm("v_cvt_pk_bf16_f32 %0, %1, %2" : "=v"(r) : "v"(lo), "v"(hi));
    return r;
}

// async global->LDS, 16B/lane; lds dst = wave-uniform base, lands at base+lane*16
__device__ __forceinline__ void cp16(const unsigned short* g, unsigned short* l) {
    __builtin_amdgcn_global_load_lds(
        (const __attribute__((address_space(1))) unsigned int*)(const void*)g,
        (__attribute__((address_space(3))) unsigned int*)(void*)l,
        16, 0, 0);
}
// XOR-swizzle: LDS 16B-chunk slot c of row r holds global chunk c^(r&7).
// Staging: lane fetches global chunk (lane&7)^(lrow&7); reads use chunk^(row&7).

// ---------------------------------------------------------------------------
// Kernel 0: one-time fp32->bf16 convert. H,Wq|Wk|Wv -> d_out scratch (dead
// until out_gemm writes); Wo -> WoB in d_ws.
// ---------------------------------------------------------------------------
#define H_CHUNKS  (MTOT * ED / 4)            // 1572864 float4s
#define W_CHUNKS  (ED * ED / 4)              // 147456 per weight
#define CVT_TOTAL (H_CHUNKS + 4 * W_CHUNKS)  // 2162688 = 8448 * 256

__global__ __launch_bounds__(256) void convert_bf16(
    const float* __restrict__ H,  const float* __restrict__ Wq,
    const float* __restrict__ Wk, const float* __restrict__ Wv,
    const float* __restrict__ Wo, unsigned short* __restrict__ dst,
    unsigned short* __restrict__ WoB) {
    int i4 = blockIdx.x * 256 + threadIdx.x;
    float4 v;
    ushort4* optr;
    if (i4 < H_CHUNKS) { v = ((const float4*)H)[i4]; optr = (ushort4*)dst + i4; }
    else {
        int j = i4 - H_CHUNKS;
        if (j < 3 * W_CHUNKS) {
            if (j < W_CHUNKS)          v = ((const float4*)Wq)[j];
            else if (j < 2 * W_CHUNKS) v = ((const float4*)Wk)[j - W_CHUNKS];
            else                       v = ((const float4*)Wv)[j - 2 * W_CHUNKS];
            optr = (ushort4*)dst + i4;
        } else {
            v = ((const float4*)Wo)[j - 3 * W_CHUNKS];
            optr = (ushort4*)WoB + (j - 3 * W_CHUNKS);
        }
    }
    ushort4 o;
    o.x = f2bf(v.x); o.y = f2bf(v.y); o.z = f2bf(v.z); o.w = f2bf(v.w);
    *optr = o;
}

// ---------------------------------------------------------------------------
// Kernel 1: QKV projection. Round-14: 64x128 tiles (was 128x128) — same
// occupancy/tail repair that paid on out_gemm (r13): LDS 32->24KB lifts the
// LDS cap 4->5 blocks/CU (16->20 waves), grid 18x128 = 2304 blocks (9/CU,
// no half-empty tail generation vs 1152 = 4.5/CU). Inner loop, staging and
// swizzles identical to the verified r13 out_gemm shape; epilogue branches
// re-indexed for wm*32 / mi<2.
// Bijective XCD swizzle (2304%8==0, 288 tiles/XCD).
// Q written pre-scaled by C2.  Q,K -> [b][h][s][d];  V -> [b][h][d][s].
// ---------------------------------------------------------------------------
__global__ __launch_bounds__(256) void qkv_gemm(
    const unsigned short* __restrict__ Hb,   // [8192][768] bf16
    const unsigned short* __restrict__ Wb,   // [2304][768] bf16 (Wq|Wk|Wv)
    unsigned short* __restrict__ qkv) {
    __shared__ __align__(16) unsigned short Ah[64 * 64];     // 8KB
    __shared__ __align__(16) unsigned short Bh[128 * 64];    // 16KB
    const int t = threadIdx.x, w = t >> 6, lane = t & 63;
    const int quad = lane >> 4, r16 = lane & 15;
    const int wm = w & 1, wn = w >> 1;       // 2 M-halves x 2 N-halves
    // XCD-aware bijective remap (nwg=2304, nwg%8==0)
    const int lin = blockIdx.y * 18 + blockIdx.x;
    const int swz = (lin & 7) * 288 + (lin >> 3);
    const int bx = swz % 18, by = swz / 18;
    const int m0 = by * 64, n0g = bx * 128;
    const int wsel = n0g / ED, n0 = n0g % ED;
    const int lrow = lane >> 3;
    const int lchs = ((lane & 7) ^ (lrow & 7)) * 8;   // swizzled source chunk

    f32x4 acc[2][4] = {};
    for (int kt = 0; kt < ED / 64; ++kt) {
        const int k0 = kt * 64;
#pragma unroll
        for (int i = 0; i < 2; ++i) {        // A: 64 rows
            int row = i * 32 + w * 8;
            cp16(&Hb[(size_t)(m0 + row + lrow) * ED + k0 + lchs], &Ah[row * 64]);
        }
#pragma unroll
        for (int i = 0; i < 4; ++i) {        // B: 128 rows
            int row = i * 32 + w * 8;
            cp16(&Wb[(size_t)(n0g + row + lrow) * ED + k0 + lchs], &Bh[row * 64]);
        }
        __syncthreads();
#pragma unroll
        for (int kk = 0; kk < 2; ++kk) {
            bf16x8 aF[2], bF[4];
#pragma unroll
            for (int mi = 0; mi < 2; ++mi) {
                int R = wm * 32 + mi * 16 + r16;
                aF[mi] = *(const bf16x8*)&Ah[R * 64 + (((kk * 4 + quad) ^ (r16 & 7)) * 8)];
            }
#pragma unroll
            for (int ni = 0; ni < 4; ++ni) {
                int R = wn * 64 + ni * 16 + r16;
                bF[ni] = *(const bf16x8*)&Bh[R * 64 + (((kk * 4 + quad) ^ (r16 & 7)) * 8)];
            }
            if (wsel == 2) {   // V: compute C^T so V^T stores stay coalesced
#pragma unroll
                for (int mi = 0; mi < 2; ++mi)
#pragma unroll
                    for (int ni = 0; ni < 4; ++ni)
                        acc[mi][ni] = __builtin_amdgcn_mfma_f32_16x16x32_bf16(
                            bF[ni], aF[mi], acc[mi][ni], 0, 0, 0);
            } else {
#pragma unroll
                for (int mi = 0; mi < 2; ++mi)
#pragma unroll
                    for (int ni = 0; ni < 4; ++ni)
                        acc[mi][ni] = __builtin_amdgcn_mfma_f32_16x16x32_bf16(
                            aF[mi], bF[ni], acc[mi][ni], 0, 0, 0);
            }
        }
        __syncthreads();
    }
    const size_t WSZ = (size_t)BHT * SEQ * HD;
    if (wsel == 2) {
#pragma unroll
        for (int mi = 0; mi < 2; ++mi)
#pragma unroll
            for (int ni = 0; ni < 4; ++ni)
#pragma unroll
                for (int r = 0; r < 4; ++r) {
                    int m  = m0 + wm * 32 + mi * 16 + r16;
                    int nn = n0 + wn * 64 + ni * 16 + quad * 4 + r;
                    int b = m >> 12, s = m & 4095;
                    int hh = nn >> 6, dd = nn & 63;
                    qkv[2 * WSZ + (((size_t)b * NH + hh) * HD + dd) * SEQ + s] =
                        f2bf(acc[mi][ni][r]);
                }
    } else {
        const float sc = (wsel == 0) ? C2 : 1.0f;
#pragma unroll
        for (int mi = 0; mi < 2; ++mi)
#pragma unroll
            for (int ni = 0; ni < 4; ++ni)
#pragma unroll
                for (int r = 0; r < 4; ++r) {
                    int m = m0 + wm * 32 + mi * 16 + quad * 4 + r;
                    int b = m >> 12, s = m & 4095;
                    int nn = n0 + wn * 64 + ni * 16 + r16;
                    int hh = nn >> 6, dd = nn & 63;
                    size_t off = (((size_t)b * NH + hh) * SEQ + s) * HD + dd;
                    qkv[(size_t)wsel * WSZ + off] = f2bf(acc[mi][ni][r] * sc);
                }
    }
}

// ---------------------------------------------------------------------------
// Kernel 2: flash attention — round-1 body verbatim (measured best, ~148-150us;
// plateau confirmed across r4-r11 structural variants, all closed).
// ---------------------------------------------------------------------------
__global__ __launch_bounds__(256) void flash_attn(
    const unsigned short* __restrict__ qkv, const float* __restrict__ mask,
    unsigned short* __restrict__ ctx) {
    __shared__ __align__(16) unsigned short Ksm[2][64 * 64];   // [key][dim], swizzled
    __shared__ __align__(16) unsigned short Vtsm[2][64 * 64];  // [dim][key], swizzled
    __shared__ __align__(16) unsigned short Mall[SEQ];         // log2-domain bf16 mask
    const int t  = threadIdx.x;
    const int bh = blockIdx.y;
    const int b  = bh / NH;
    const int h  = bh % NH;
    const int qbase = blockIdx.x * 128;
    const size_t WSZ = (size_t)BHT * SEQ * HD;
    const unsigned short* Qp = qkv + (size_t)bh * SEQ * HD;
    const unsigned short* Kp = Qp + WSZ;
    const unsigned short* Vt = qkv + 2 * WSZ + (size_t)bh * HD * SEQ;
    const int w = t >> 6, lane = t & 63, n31 = lane & 31, hi = lane >> 5;
    const int lrow = lane >> 3;
    const int lchs = ((lane & 7) ^ (lrow & 7)) * 8;

    bf16x8 qF[4];
    {
        int qrow = qbase + w * 32 + n31;
#pragma unroll
        for (int kc = 0; kc < 4; ++kc)
            qF[kc] = *(const bf16x8*)&Qp[(size_t)qrow * HD + kc * 16 + hi * 8];
    }
    bf16x8 bOnes = {};
    if (hi == 0) bOnes[0] = (short)0x3F80;   // 1.0 at k==0

    // one-time: whole mask row for this batch -> LDS, log2 domain, bf16
#pragma unroll
    for (int i = 0; i < 4; ++i) {
        float4 mv = ((const float4*)(mask + (size_t)b * SEQ))[i * 256 + t];
        ushort4 o;
        o.x = f2bf(LOG2E * mv.x); o.y = f2bf(LOG2E * mv.y);
        o.z = f2bf(LOG2E * mv.z); o.w = f2bf(LOG2E * mv.w);
        *(ushort4*)&Mall[(i * 256 + t) * 4] = o;
    }

    // prologue: stage tile 0 into buffer 0
#pragma unroll
    for (int i = 0; i < 2; ++i) {
        int row = w * 16 + i * 8;
        cp16(&Kp[(size_t)(row + lrow) * HD + lchs], &Ksm[0][row * 64]);
        cp16(&Vt[(size_t)(row + lrow) * SEQ + lchs], &Vtsm[0][row * 64]);
    }
    __syncthreads();

    f32x16 oAcc[2] = {};
    float l_i = 0.0f;
    const int sw = n31 & 7;                  // row-swizzle for frag reads
    int cur = 0;

    for (int kt = 0; kt < SEQ / 64; ++kt) {
        // issue next-tile loads first: they fly during this tile's compute
        if (kt + 1 < SEQ / 64) {
#pragma unroll
            for (int i = 0; i < 2; ++i) {
                int row = w * 16 + i * 8;
                cp16(&Kp[(size_t)((kt + 1) * 64 + row + lrow) * HD + lchs],
                     &Ksm[cur ^ 1][row * 64]);
                cp16(&Vt[(size_t)(row + lrow) * SEQ + (kt + 1) * 64 + lchs],
                     &Vtsm[cur ^ 1][row * 64]);
            }
        }

        // S^T = K Q^T (log2 domain) + mask via MFMA C-init
        float p[2][16];
        float rs0 = 0.f, rs1 = 0.f, rs2 = 0.f, rs3 = 0.f;
#pragma unroll
        for (int st = 0; st < 2; ++st) {
            bf16x8 am = {};
            {
                unsigned short mv = Mall[kt * 64 + st * 32 + n31];
                am[0] = (hi == 0) ? (short)mv : (short)0;
            }
            f32x16 sA = {};
            sA = __builtin_amdgcn_mfma_f32_32x32x16_bf16(am, bOnes, sA, 0, 0, 0);
            __builtin_amdgcn_s_setprio(1);
#pragma unroll
            for (int kc = 0; kc < 4; ++kc) {
                bf16x8 kF = *(const bf16x8*)
                    &Ksm[cur][(st * 32 + n31) * 64 + (((2 * kc + hi) ^ sw) * 8)];
                sA = __builtin_amdgcn_mfma_f32_32x32x16_bf16(kF, qF[kc], sA, 0, 0, 0);
            }
            __builtin_amdgcn_s_setprio(0);
#pragma unroll
            for (int r = 0; r < 16; ++r) p[st][r] = __builtin_amdgcn_exp2f(sA[r]);
            rs0 += p[st][0] + p[st][4] + p[st][8]  + p[st][12];
            rs1 += p[st][1] + p[st][5] + p[st][9]  + p[st][13];
            rs2 += p[st][2] + p[st][6] + p[st][10] + p[st][14];
            rs3 += p[st][3] + p[st][7] + p[st][11] + p[st][15];
        }
        l_i += (rs0 + rs1) + (rs2 + rs3);

        // P -> PV B-fragments fully in-register (T12).
        // p[st][r] = P[q=n31][key = st*32 + (r&3)+8*(r>>2)+4*hi].
        bf16x8 pF[4];
#pragma unroll
        for (int st = 0; st < 2; ++st) {
            uint32_t pw[8];
#pragma unroll
            for (int i = 0; i < 8; ++i)
                pw[i] = cvtpk(p[st][2 * i], p[st][2 * i + 1]);
#pragma unroll
            for (int half = 0; half < 2; ++half) {
                auto r02 = __builtin_amdgcn_permlane32_swap(
                    pw[half * 4 + 0], pw[half * 4 + 2], false, false);
                auto r13 = __builtin_amdgcn_permlane32_swap(
                    pw[half * 4 + 1], pw[half * 4 + 3], false, false);
                union { u32x4 u; bf16x8 h; } f;
                f.u[0] = r02[0]; f.u[1] = r13[0]; f.u[2] = r02[1]; f.u[3] = r13[1];
                pF[st * 2 + half] = f.h;
            }
        }

        // O^T += V^T P^T
        __builtin_amdgcn_s_setprio(1);
#pragma unroll
        for (int kc = 0; kc < 4; ++kc) {
            bf16x8 pFk = pF[kc];
#pragma unroll
            for (int dt = 0; dt < 2; ++dt) {
                bf16x8 vF = *(const bf16x8*)
                    &Vtsm[cur][(dt * 32 + n31) * 64 + (((2 * kc + hi) ^ sw) * 8)];
                oAcc[dt] = __builtin_amdgcn_mfma_f32_32x32x16_bf16(vF, pFk, oAcc[dt], 0, 0, 0);
            }
        }
        __builtin_amdgcn_s_setprio(0);

        __syncthreads();   // drains vmcnt: next tile staged; buffer flip safe
        cur ^= 1;
    }
    l_i += __shfl_xor(l_i, 32);
    float inv = 1.0f / l_i;
    int s = qbase + w * 32 + n31;
    unsigned short* obase = &ctx[((size_t)b * SEQ + s) * ED + h * HD];
#pragma unroll
    for (int dt = 0; dt < 2; ++dt)
#pragma unroll
        for (int g = 0; g < 4; ++g) {
            ushort4 o;
            o.x = f2bf(oAcc[dt][4 * g + 0] * inv);
            o.y = f2bf(oAcc[dt][4 * g + 1] * inv);
            o.z = f2bf(oAcc[dt][4 * g + 2] * inv);
            o.w = f2bf(oAcc[dt][4 * g + 3] * inv);
            *(ushort4*)&obase[dt * 32 + hi * 4 + 8 * g] = o;
        }
}

// ---------------------------------------------------------------------------
// Kernel 3: output projection — r13 kernel verbatim (measured win: 64x128
// tiles, 768 blocks ~3/CU, 24KB LDS, bijective XCD swizzle).
// out[m][n] = sum_k ctx[m][k]*Wo[n][k] + bo[n], fp32 output.
// ---------------------------------------------------------------------------
__global__ __launch_bounds__(256) void out_gemm(
    const unsigned short* __restrict__ Ab,   // ctx bf16 [8192][768]
    const unsigned short* __restrict__ Wob,  // [768][768] bf16
    const float* __restrict__ bo, float* __restrict__ out) {
    __shared__ __align__(16) unsigned short Ah[64 * 64];     // 8KB
    __shared__ __align__(16) unsigned short Bh[128 * 64];    // 16KB
    const int t = threadIdx.x, w = t >> 6, lane = t & 63;
    const int quad = lane >> 4, r16 = lane & 15;
    const int wm = w & 1, wn = w >> 1;       // 2 M-halves x 2 N-halves
    // XCD-aware bijective remap (nwg=768, nwg%8==0)
    const int lin = blockIdx.y * 6 + blockIdx.x;
    const int swz = (lin & 7) * 96 + (lin >> 3);
    const int bx = swz % 6, by = swz / 6;
    const int m0 = by * 64, n0 = bx * 128;
    const int lrow = lane >> 3;
    const int lchs = ((lane & 7) ^ (lrow & 7)) * 8;

    f32x4 acc[2][4] = {};
    for (int kt = 0; kt < ED / 64; ++kt) {
        const int k0 = kt * 64;
#pragma unroll
        for (int i = 0; i < 2; ++i) {        // A: 64 rows
            int row = i * 32 + w * 8;
            cp16(&Ab[(size_t)(m0 + row + lrow) * ED + k0 + lchs], &Ah[row * 64]);
        }
#pragma unroll
        for (int i = 0; i < 4; ++i) {        // B: 128 rows
            int row = i * 32 + w * 8;
            cp16(&Wob[(size_t)(n0 + row + lrow) * ED + k0 + lchs], &Bh[row * 64]);
        }
        __syncthreads();
#pragma unroll
        for (int kk = 0; kk < 2; ++kk) {
            bf16x8 aF[2], bF[4];
#pragma unroll
            for (int mi = 0; mi < 2; ++mi) {
                int R = wm * 32 + mi * 16 + r16;
                aF[mi] = *(const bf16x8*)&Ah[R * 64 + (((kk * 4 + quad) ^ (r16 & 7)) * 8)];
            }
#pragma unroll
            for (int ni = 0; ni < 4; ++ni) {
                int R = wn * 64 + ni * 16 + r16;
                bF[ni] = *(const bf16x8*)&Bh[R * 64 + (((kk * 4 + quad) ^ (r16 & 7)) * 8)];
            }
#pragma unroll
            for (int mi = 0; mi < 2; ++mi)
#pragma unroll
                for (int ni = 0; ni < 4; ++ni)
                    acc[mi][ni] = __builtin_amdgcn_mfma_f32_16x16x32_bf16(
                        aF[mi], bF[ni], acc[mi][ni], 0, 0, 0);
        }
        __syncthreads();
    }
    float bov[4];
#pragma unroll
    for (int ni = 0; ni < 4; ++ni) bov[ni] = bo[n0 + wn * 64 + ni * 16 + r16];
#pragma unroll
    for (int mi = 0; mi < 2; ++mi)
#pragma unroll
        for (int ni = 0; ni < 4; ++ni)
#pragma unroll
            for (int r = 0; r < 4; ++r) {
                int m = m0 + wm * 32 + mi * 16 + quad * 4 + r;
                int n = n0 + wn * 64 + ni * 16 + r16;
                out[(size_t)m * ED + n] = acc[mi][ni][r] + bov[ni];
            }
}

// ---------------------------------------------------------------------------
extern "C" void kernel_launch(void* const* d_in, const int* in_sizes, int n_in,
                              void* d_out, int out_size, void* d_ws, size_t ws_size,
                              hipStream_t stream) {
    const float* H    = (const float*)d_in[0];
    const float* mask = (const float*)d_in[1];
    const float* Wq   = (const float*)d_in[2];
    const float* Wk   = (const float*)d_in[3];
    const float* Wv   = (const float*)d_in[4];
    const float* Wo   = (const float*)d_in[5];
    const float* bo   = (const float*)d_in[6];
    unsigned short* ws = (unsigned short*)d_ws;
    const size_t WSZ = (size_t)BHT * SEQ * HD;
    unsigned short* qkv = ws;                           // 3*WSZ bf16
    unsigned short* ctx = ws + 3 * WSZ;                 // [8192][768] bf16
    unsigned short* WoB = ctx + (size_t)MTOT * ED;      // [768][768] bf16
    float* out = (float*)d_out;
    // d_out doubles as scratch for bf16 H and Wqkv until out_gemm overwrites it
    unsigned short* Hb = (unsigned short*)d_out;        // 6291456 elems
    unsigned short* Wb = Hb + (size_t)MTOT * ED;        // 1769472 elems

    convert_bf16<<<CVT_TOTAL / 256, 256, 0, stream>>>(H, Wq, Wk, Wv, Wo, Hb, WoB);
    qkv_gemm<<<dim3(3 * ED / 128, MTOT / 64), 256, 0, stream>>>(Hb, Wb, qkv);
    flash_attn<<<dim3(SEQ / 128, BHT), 256, 0, stream>>>(qkv, mask, ctx);
    out_gemm<<<dim3(ED / 128, MTOT / 64), 256, 0, stream>>>(ctx, WoB, bo, out);
}